// Round 8
// baseline (419.463 us; speedup 1.0000x reference)
//
#include <hip/hip_runtime.h>
#include <hip/hip_bf16.h>
#include <math.h>

typedef __bf16 bf16;
typedef __attribute__((ext_vector_type(8))) __bf16 bf16x8;
typedef __attribute__((ext_vector_type(4))) __bf16 bf16x4;
typedef __attribute__((ext_vector_type(4))) float f32x4;
typedef __attribute__((ext_vector_type(4))) short short4v;

#define HDIM 1024
#define NHEAD 16
#define HD 64
#define FFDIM 4096
#define BATCH 2
#define SEQ 2048
#define M_TOK 4096  // BATCH*SEQ
#define NSPLIT 2
#define PSTRIDE ((size_t)M_TOK * HDIM)  // f32 elements between split-K partials (16 MiB)

static __device__ __forceinline__ void async_load16(const bf16* g, bf16* l) {
  __builtin_amdgcn_global_load_lds(
      (const __attribute__((address_space(1))) void*)g,
      (__attribute__((address_space(3))) void*)l, 16, 0, 0);
}

// 16x16x16 bf16 MFMA wrapper. Host pass has no amdgcn builtins -> gate on
// __HIP_DEVICE_COMPILE__ (R5 lesson: bare #error breaks host compilation).
static __device__ __forceinline__ f32x4 mfma16_bf16(bf16x4 a, bf16x4 b, f32x4 c) {
#if defined(__HIP_DEVICE_COMPILE__)
#if __has_builtin(__builtin_amdgcn_mfma_f32_16x16x16bf16_1k)
  return __builtin_amdgcn_mfma_f32_16x16x16bf16_1k(
      __builtin_bit_cast(short4v, a), __builtin_bit_cast(short4v, b), c, 0, 0, 0);
#else
  return __builtin_amdgcn_mfma_f32_16x16x16_bf16(a, b, c, 0, 0, 0);
#endif
#else
  return c;  // host pass: never executed
#endif
}

// ---------------------------------------------------------------- prep: all transposes + x cast
__global__ __launch_bounds__(256)
void prep_kernel(const float* __restrict__ x,
                 const float* __restrict__ Wq, const float* __restrict__ Wk,
                 const float* __restrict__ Wv, const float* __restrict__ Wo,
                 const float* __restrict__ W1, const float* __restrict__ W2,
                 bf16* __restrict__ Xb, bf16* __restrict__ QKVT,
                 bf16* __restrict__ W1T, bf16* __restrict__ W2T)
{
  const int z = blockIdx.z;
  const int t = threadIdx.x;
  if (z == 12) {
    const size_t base = ((size_t)(blockIdx.y * 32 + blockIdx.x)) * 4096;
#pragma unroll
    for (int j = 0; j < 4; ++j) {
      const size_t i = base + j * 1024 + t * 4;
      f32x4 v = *(const f32x4*)(x + i);
      bf16x4 o;
#pragma unroll
      for (int k = 0; k < 4; ++k) o[k] = (bf16)v[k];
      *(bf16x4*)(Xb + i) = o;
    }
    return;
  }
  const float* ps; bf16* pd; int sld, dld;
  if (z < 4) {
    ps = (z == 0) ? Wq : (z == 1) ? Wk : (z == 2) ? Wv : Wo;
    pd = QKVT + (size_t)z * HDIM * HDIM; sld = 1024; dld = 1024;
  } else if (z < 8) {
    const int c = z - 4;
    ps = W1 + c * 1024; sld = 4096;
    pd = W1T + (size_t)c * 1024 * 1024; dld = 1024;
  } else {
    const int c = z - 8;
    ps = W2 + (size_t)c * 1024 * 1024; sld = 1024;
    pd = W2T + c * 1024; dld = 4096;
  }
  __shared__ float tile[32][33];
  const int tx = t & 31, ty = t >> 5;
  const int c0 = blockIdx.x * 32, r0 = blockIdx.y * 32;
#pragma unroll
  for (int i = 0; i < 32; i += 8)
    tile[ty + i][tx] = ps[(size_t)(r0 + ty + i) * sld + c0 + tx];
  __syncthreads();
#pragma unroll
  for (int i = 0; i < 32; i += 8)
    pd[(size_t)(c0 + ty + i) * dld + r0 + tx] = (bf16)tile[tx][ty + i];
}

// ---------------------------------------------------------------- GEMM  C = A @ Bt^T (+ bias)
// Operand-swapped MFMA: lane holds 4 consecutive output columns -> vector stores.
// EPI: 1 = f32 partial, 2 = bias+gelu->bf16, 3 = QKV fused epilogue
// (V section writes fragment-friendly VB[bh][key/16][d][key%16] layout)
template<int EPI>
__global__ __launch_bounds__(256)
void gemm_bt(const bf16* __restrict__ A, const bf16* __restrict__ Bt,
             const float* __restrict__ b0, const float* __restrict__ b1p,
             const float* __restrict__ b2p, void* __restrict__ Cout,
             int M, int N, int ldk, int kchunk)
{
  __shared__ __align__(16) bf16 As[128 * 64];
  __shared__ __align__(16) bf16 Bs[128 * 64];
  const int t = threadIdx.x;
  const int wave = t >> 6, lane = t & 63;
  const int lm = lane & 15, qd = lane >> 4;
  const int wm = (wave >> 1) * 64, wn = (wave & 1) * 64;
  const int bm = blockIdx.y * 128, bn = blockIdx.x * 128;
  const int kbeg = blockIdx.z * kchunk;

  f32x4 acc[4][4] = {};
  const int srow = t >> 3;
  const int schk = t & 7;

  for (int k0 = kbeg; k0 < kbeg + kchunk; k0 += 64) {
#pragma unroll
    for (int r = 0; r < 4; ++r) {
      const int row = r * 32 + srow;
      const int chunk = schk ^ (row & 7);
      async_load16(A + (size_t)(bm + row) * ldk + (k0 + chunk * 8),
                   (bf16*)((char*)As + r * 4096 + t * 16));
    }
#pragma unroll
    for (int r = 0; r < 4; ++r) {
      const int row = r * 32 + srow;
      const int chunk = schk ^ (row & 7);
      async_load16(Bt + (size_t)(bn + row) * ldk + (k0 + chunk * 8),
                   (bf16*)((char*)Bs + r * 4096 + t * 16));
    }
    __syncthreads();
#pragma unroll
    for (int ks = 0; ks < 2; ++ks) {
      bf16x8 av[4], bv[4];
#pragma unroll
      for (int mt = 0; mt < 4; ++mt) {
        const int row = wm + mt * 16 + lm;
        const int chunk = (ks * 4 + qd) ^ (row & 7);
        av[mt] = *(const bf16x8*)(As + row * 64 + chunk * 8);
      }
#pragma unroll
      for (int nt = 0; nt < 4; ++nt) {
        const int row = wn + nt * 16 + lm;
        const int chunk = (ks * 4 + qd) ^ (row & 7);
        bv[nt] = *(const bf16x8*)(Bs + row * 64 + chunk * 8);
      }
#pragma unroll
      for (int mt = 0; mt < 4; ++mt)
#pragma unroll
        for (int nt = 0; nt < 4; ++nt)
          acc[mt][nt] = __builtin_amdgcn_mfma_f32_16x16x32_bf16(bv[nt], av[mt], acc[mt][nt], 0, 0, 0);
    }
    __syncthreads();
  }

#pragma unroll
  for (int nt = 0; nt < 4; ++nt) {
    const int n0 = bn + wn + nt * 16 + qd * 4;
    f32x4 bsv = {0.f, 0.f, 0.f, 0.f};
    if (EPI == 2) bsv = *(const f32x4*)(b0 + n0);
    if (EPI == 3) {
      const int sect = n0 >> 10, c = n0 & 1023;
      const float* bp = (sect == 0) ? b0 : (sect == 1) ? b1p : b2p;
      bsv = *(const f32x4*)(bp + c);
    }
#pragma unroll
    for (int mt = 0; mt < 4; ++mt) {
      const int m = bm + wm + mt * 16 + lm;
      f32x4 v;
#pragma unroll
      for (int r = 0; r < 4; ++r) v[r] = acc[mt][nt][r] + bsv[r];
      if (EPI == 1) {
        *(f32x4*)((float*)Cout + (size_t)blockIdx.z * M * N + (size_t)m * N + n0) = v;
      } else if (EPI == 2) {
        bf16x4 o;
#pragma unroll
        for (int r = 0; r < 4; ++r) {
          const float z = v[r] * 0.70710678118f;
          const float az = fabsf(z);
          const float tt = __builtin_amdgcn_rcpf(fmaf(az, 0.3275911f, 1.0f));
          const float poly = tt * fmaf(tt, fmaf(tt, fmaf(tt, fmaf(tt, 1.061405429f,
                             -1.453152027f), 1.421413741f), -0.284496736f), 0.254829592f);
          const float e = __builtin_amdgcn_exp2f(az * az * -1.4426950408889634f);
          float erfv = 1.0f - poly * e;
          erfv = (z < 0.f) ? -erfv : erfv;
          o[r] = (bf16)(0.5f * v[r] * (1.0f + erfv));
        }
        *(bf16x4*)((bf16*)Cout + (size_t)m * N + n0) = o;
      } else {
        bf16* base = (bf16*)Cout;
        const int sect = n0 >> 10, c = n0 & 1023;
        if (sect < 2) {
          bf16x4 o;
#pragma unroll
          for (int r = 0; r < 4; ++r) o[r] = (bf16)v[r];
          *(bf16x4*)(base + (size_t)sect * M_TOK * HDIM + (size_t)m * HDIM + c) = o;
        } else {
          // VB layout: [bh][key>>4][d][key&15]
          const int hh = c >> 6, d0 = c & 63;
          const int bb = m >> 11, ss = m & 2047;
          const int kb = ss >> 4, j = ss & 15;
          bf16* vb = base + (size_t)2 * M_TOK * HDIM +
                     (size_t)(bb * NHEAD + hh) * (SEQ / 16) * HD * 16;
#pragma unroll
          for (int r = 0; r < 4; ++r)
            vb[((size_t)kb * HD + d0 + r) * 16 + j] = (bf16)v[r];
        }
      }
    }
  }
}

// ---------------------------------------------------------------- flash attention v4
// No LDS, no barriers. K/V/mask fragments load directly global->VGPR (K rows
// coalesced 64B; VB layout gives contiguous 512B per V-fragment load).
// Transposed, no-max, split-KV; P stays in registers (C-layout == 16x16x16
// B-layout). 32 q per wave (2 q-tiles share K/V/mask frags).
// grid (SEQ/128, 32 bh, NSPLIT), 256 thr.
__global__ __launch_bounds__(256)
void attn_kernel(const bf16* __restrict__ Q, const bf16* __restrict__ Kg,
                 const bf16* __restrict__ VB, const int* __restrict__ mask,
                 float* __restrict__ Po, float* __restrict__ Lp)
{
  const int t = threadIdx.x;
  const int wave = t >> 6, lane = t & 63;
  const int lm = lane & 15, qd = lane >> 4;
  const int bh = blockIdx.y;
  const int b = bh >> 4, h = bh & 15;
  const int q0 = blockIdx.x * 128 + wave * 32;
  const int split = blockIdx.z;
  const int kv_beg = split * (SEQ / NSPLIT);

  bf16x8 qf[2][2];
#pragma unroll
  for (int qt = 0; qt < 2; ++qt)
#pragma unroll
    for (int ks = 0; ks < 2; ++ks)
      qf[qt][ks] = *(const bf16x8*)(Q + (size_t)(b * SEQ + q0 + qt * 16 + lm) * HDIM +
                                    h * HD + ks * 32 + qd * 8);

  const bf16* Kp = Kg + (size_t)(b * SEQ + kv_beg + lm) * HDIM + h * HD + qd * 8;
  const bf16* Vp = VB + (size_t)bh * (SEQ / 16) * HD * 16 +
                   (size_t)(kv_beg >> 4) * (HD * 16) + lm * 16 + qd * 4;
  const int* Mp = mask + b * SEQ + kv_beg + qd * 4;

  float l_lane[2] = {0.f, 0.f};
  f32x4 oacc[2][4] = {};
  const float C = 0.1803368801f;  // log2(e)/8

  for (int it = 0; it < (SEQ / NSPLIT) / 64; ++it) {
    bf16x8 kf[2][4];
#pragma unroll
    for (int nt = 0; nt < 4; ++nt)
#pragma unroll
      for (int ks = 0; ks < 2; ++ks)
        kf[ks][nt] = *(const bf16x8*)(Kp + (size_t)nt * 16 * HDIM + ks * 32);

    bf16x4 vf[4][4];  // [nt2 d-block][nt key-block]
#pragma unroll
    for (int nt2 = 0; nt2 < 4; ++nt2)
#pragma unroll
      for (int nt = 0; nt < 4; ++nt)
        vf[nt2][nt] = *(const bf16x4*)(Vp + nt * (16 * HD * 16 / 16) + nt2 * 256);

    int4 mi[4];
#pragma unroll
    for (int nt = 0; nt < 4; ++nt) mi[nt] = *(const int4*)(Mp + nt * 16);

    bf16x4 pf[2][4];
#pragma unroll
    for (int qt = 0; qt < 2; ++qt) {
      f32x4 sacc[4] = {};
#pragma unroll
      for (int ks = 0; ks < 2; ++ks)
#pragma unroll
        for (int nt = 0; nt < 4; ++nt)
          sacc[nt] = __builtin_amdgcn_mfma_f32_16x16x32_bf16(kf[ks][nt], qf[qt][ks], sacc[nt], 0, 0, 0);
#pragma unroll
      for (int nt = 0; nt < 4; ++nt) {
        const int* mv = (const int*)&mi[nt];
#pragma unroll
        for (int r = 0; r < 4; ++r) {
          const float ma = (mv[r] == 1) ? 0.f : -1.0e30f;
          const float pv = __builtin_amdgcn_exp2f(fmaf(sacc[nt][r], C, ma));
          l_lane[qt] += pv;
          pf[qt][nt][r] = (bf16)pv;
        }
      }
    }

#pragma unroll
    for (int nt2 = 0; nt2 < 4; ++nt2)
#pragma unroll
      for (int nt = 0; nt < 4; ++nt)
#pragma unroll
        for (int qt = 0; qt < 2; ++qt)
          oacc[qt][nt2] = mfma16_bf16(vf[nt2][nt], pf[qt][nt], oacc[qt][nt2]);

    Kp += (size_t)64 * HDIM;
    Vp += 4 * (HD * 16);   // 4 key-blocks of 16 keys
    Mp += 64;
  }

  float* po = Po + (size_t)(split * 32 + bh) * 64 * SEQ;
#pragma unroll
  for (int qt = 0; qt < 2; ++qt) {
    float l = l_lane[qt];
    l += __shfl_xor(l, 16, 64);
    l += __shfl_xor(l, 32, 64);
#pragma unroll
    for (int nt2 = 0; nt2 < 4; ++nt2)
#pragma unroll
      for (int r = 0; r < 4; ++r)
        po[(size_t)(nt2 * 16 + qd * 4 + r) * SEQ + q0 + qt * 16 + lm] = oacc[qt][nt2][r];
    if (qd == 0)
      Lp[(size_t)(split * 32 + bh) * SEQ + q0 + qt * 16 + lm] = l;
  }
}

// ---------------------------------------------------------------- attn merge: O=(O0+O1)/(l0+l1)
__global__ __launch_bounds__(256)
void attn_merge(const float* __restrict__ Po, const float* __restrict__ Lp,
                bf16* __restrict__ Aout)
{
  const int t = threadIdx.x;
  const int bh = blockIdx.y;
  const int b = bh >> 4, h = bh & 15;
  const int s0 = blockIdx.x * 64;
  const int tok = t >> 2;
  const int dc = (t & 3) * 16;

  const float l = Lp[(size_t)bh * SEQ + s0 + tok] +
                  Lp[(size_t)(32 + bh) * SEQ + s0 + tok];
  const float inv = 1.0f / l;

  const float* p0 = Po + ((size_t)bh * 64) * SEQ + s0 + tok;
  const float* p1 = Po + ((size_t)(32 + bh) * 64) * SEQ + s0 + tok;
  bf16x8 o0, o1;
#pragma unroll
  for (int j = 0; j < 8; ++j)
    o0[j] = (bf16)((p0[(size_t)(dc + j) * SEQ] + p1[(size_t)(dc + j) * SEQ]) * inv);
#pragma unroll
  for (int j = 8; j < 16; ++j)
    o1[j - 8] = (bf16)((p0[(size_t)(dc + j) * SEQ] + p1[(size_t)(dc + j) * SEQ]) * inv);

  bf16* dst = Aout + (size_t)(b * SEQ + s0 + tok) * HDIM + h * HD + dc;
  *(bf16x8*)dst = o0;
  *(bf16x8*)(dst + 8) = o1;
}

// ------------------------------------------- layernorm over H=1024, summing NP partials + bias
template<int NP, int OUT_BF16>
__global__ __launch_bounds__(256)
void ln_sum(const float* __restrict__ p, const float* __restrict__ bias,
            const float* __restrict__ gamma, const float* __restrict__ beta,
            void* __restrict__ out)
{
  const int row = blockIdx.x;
  const int t = threadIdx.x;
  f32x4 v = *(const f32x4*)(p + (size_t)row * HDIM + t * 4);
#pragma unroll
  for (int np = 1; np < NP; ++np) {
    f32x4 u = *(const f32x4*)(p + np * PSTRIDE + (size_t)row * HDIM + t * 4);
#pragma unroll
    for (int j = 0; j < 4; ++j) v[j] += u[j];
  }
  f32x4 bv0 = *(const f32x4*)(bias + t * 4);
#pragma unroll
  for (int j = 0; j < 4; ++j) v[j] += bv0[j];

  float s = v[0] + v[1] + v[2] + v[3];
  float s2 = v[0] * v[0] + v[1] * v[1] + v[2] * v[2] + v[3] * v[3];
#pragma unroll
  for (int d = 1; d < 64; d <<= 1) { s += __shfl_xor(s, d, 64); s2 += __shfl_xor(s2, d, 64); }
  __shared__ float ss[4], ss2[4];
  const int wave = t >> 6, lane = t & 63;
  if (lane == 0) { ss[wave] = s; ss2[wave] = s2; }
  __syncthreads();
  s = ss[0] + ss[1] + ss[2] + ss[3];
  s2 = ss2[0] + ss2[1] + ss2[2] + ss2[3];
  const float mean = s * (1.0f / HDIM);
  const float var = s2 * (1.0f / HDIM) - mean * mean;
  const float rstd = rsqrtf(var + 1e-12f);
  f32x4 gv = *(const f32x4*)(gamma + t * 4);
  f32x4 bv = *(const f32x4*)(beta + t * 4);
  f32x4 y;
#pragma unroll
  for (int j = 0; j < 4; ++j) y[j] = gv[j] * (v[j] - mean) * rstd + bv[j];
  if (OUT_BF16) {
    bf16x4 o;
#pragma unroll
    for (int j = 0; j < 4; ++j) o[j] = (bf16)y[j];
    *(bf16x4*)((bf16*)out + (size_t)row * HDIM + t * 4) = o;
  } else {
    *(f32x4*)((float*)out + (size_t)row * HDIM + t * 4) = y;
  }
}

// ---------------------------------------------------------------- launch
extern "C" void kernel_launch(void* const* d_in, const int* in_sizes, int n_in,
                              void* d_out, int out_size, void* d_ws, size_t ws_size,
                              hipStream_t stream)
{
  const float* x    = (const float*)d_in[0];
  const int*   am   = (const int*)d_in[1];
  const float* Wq   = (const float*)d_in[2];
  const float* bq   = (const float*)d_in[3];
  const float* Wk   = (const float*)d_in[4];
  const float* bk   = (const float*)d_in[5];
  const float* Wv   = (const float*)d_in[6];
  const float* bv   = (const float*)d_in[7];
  const float* Wo   = (const float*)d_in[8];
  const float* bo   = (const float*)d_in[9];
  const float* ln1g = (const float*)d_in[10];
  const float* ln1b = (const float*)d_in[11];
  const float* W1   = (const float*)d_in[12];
  const float* b1   = (const float*)d_in[13];
  const float* W2   = (const float*)d_in[14];
  const float* b2   = (const float*)d_in[15];
  const float* ln2g = (const float*)d_in[16];
  const float* ln2b = (const float*)d_in[17];

  char* ws = (char*)d_ws;
  const size_t MB = 1ull << 20;
  bf16*  W1T  = (bf16*)(ws + 0 * MB);    // 8 MiB
  bf16*  W2T  = (bf16*)(ws + 8 * MB);    // 8 MiB
  bf16*  Xb   = (bf16*)(ws + 16 * MB);   // 8 MiB (dead after QKV)
  bf16*  QKVT = (bf16*)(ws + 24 * MB);   // 8 MiB (WoT = last quarter)
  bf16*  WoT  = QKVT + (size_t)3 * HDIM * HDIM;
  bf16*  Qb   = (bf16*)(ws + 33 * MB);   // Q(33-41), K(41-49), VB(49-57)
  bf16*  Kb   = (bf16*)(ws + 41 * MB);
  bf16*  VBb  = (bf16*)(ws + 49 * MB);
  float* Po   = (float*)(ws + 57 * MB);  // 32 MiB attn O^T partials (57-89)
  float* Lp   = (float*)(ws + 89 * MB);  // 0.5 MiB l partials
  bf16*  Ab   = (bf16*)(ws + 16 * MB);   // merge out, reuse Xb
  float* Pw   = (float*)(ws + 33 * MB);  // Wo partials 33-65
  bf16*  L1   = (bf16*)(ws + 65 * MB);   // 8 MiB
  bf16*  F1   = (bf16*)(ws + 16 * MB);   // 32 MiB (16-48)
  float* Pf   = (float*)(ws + 48 * MB);  // FFN2 partials

  prep_kernel<<<dim3(32, 32, 13), 256, 0, stream>>>(x, Wq, Wk, Wv, Wo, W1, W2,
                                                    Xb, QKVT, W1T, W2T);

  gemm_bt<3><<<dim3(3072 / 128, M_TOK / 128, 1), 256, 0, stream>>>(
      Xb, QKVT, bq, bk, bv, Qb, M_TOK, 3072, HDIM, HDIM);

  attn_kernel<<<dim3(SEQ / 128, BATCH * NHEAD, NSPLIT), 256, 0, stream>>>(
      Qb, Kb, VBb, am, Po, Lp);
  attn_merge<<<dim3(SEQ / 64, BATCH * NHEAD), 256, 0, stream>>>(Po, Lp, Ab);

  gemm_bt<1><<<dim3(HDIM / 128, M_TOK / 128, 2), 256, 0, stream>>>(
      Ab, WoT, nullptr, nullptr, nullptr, Pw, M_TOK, HDIM, HDIM, 512);
  ln_sum<2, 1><<<M_TOK, 256, 0, stream>>>(Pw, bo, ln1g, ln1b, L1);

  gemm_bt<2><<<dim3(FFDIM / 128, M_TOK / 128, 1), 256, 0, stream>>>(
      L1, W1T, b1, nullptr, nullptr, F1, M_TOK, FFDIM, HDIM, HDIM);

  if (ws_size >= 113 * MB) {
    gemm_bt<1><<<dim3(HDIM / 128, M_TOK / 128, 4), 256, 0, stream>>>(
        F1, W2T, nullptr, nullptr, nullptr, Pf, M_TOK, HDIM, FFDIM, 1024);
    ln_sum<4, 0><<<M_TOK, 256, 0, stream>>>(Pf, b2, ln2g, ln2b, (float*)d_out);
  } else {
    gemm_bt<1><<<dim3(HDIM / 128, M_TOK / 128, 2), 256, 0, stream>>>(
        F1, W2T, nullptr, nullptr, nullptr, Pf, M_TOK, HDIM, FFDIM, 2048);
    ln_sum<2, 0><<<M_TOK, 256, 0, stream>>>(Pf, b2, ln2g, ln2b, (float*)d_out);
  }
}

// Round 9
// 380.378 us; speedup vs baseline: 1.1028x; 1.1028x over previous
//
#include <hip/hip_runtime.h>
#include <hip/hip_bf16.h>
#include <math.h>

typedef __bf16 bf16;
typedef __attribute__((ext_vector_type(8))) __bf16 bf16x8;
typedef __attribute__((ext_vector_type(4))) __bf16 bf16x4;
typedef __attribute__((ext_vector_type(4))) float f32x4;
typedef __attribute__((ext_vector_type(4))) short short4v;

#define HDIM 1024
#define NHEAD 16
#define HD 64
#define FFDIM 4096
#define BATCH 2
#define SEQ 2048
#define M_TOK 4096  // BATCH*SEQ
#define NSPLIT 2
#define PSTRIDE ((size_t)M_TOK * HDIM)  // f32 elements between split-K partials (16 MiB)

static __device__ __forceinline__ void async_load16(const bf16* g, bf16* l) {
  __builtin_amdgcn_global_load_lds(
      (const __attribute__((address_space(1))) void*)g,
      (__attribute__((address_space(3))) void*)l, 16, 0, 0);
}

// 16x16x16 bf16 MFMA wrapper. Host pass has no amdgcn builtins -> gate on
// __HIP_DEVICE_COMPILE__ (R5 lesson: bare #error breaks host compilation).
static __device__ __forceinline__ f32x4 mfma16_bf16(bf16x4 a, bf16x4 b, f32x4 c) {
#if defined(__HIP_DEVICE_COMPILE__)
#if __has_builtin(__builtin_amdgcn_mfma_f32_16x16x16bf16_1k)
  return __builtin_amdgcn_mfma_f32_16x16x16bf16_1k(
      __builtin_bit_cast(short4v, a), __builtin_bit_cast(short4v, b), c, 0, 0, 0);
#else
  return __builtin_amdgcn_mfma_f32_16x16x16_bf16(a, b, c, 0, 0, 0);
#endif
#else
  return c;  // host pass: never executed
#endif
}

// ---------------------------------------------------------------- prep: all transposes + x cast
__global__ __launch_bounds__(256)
void prep_kernel(const float* __restrict__ x,
                 const float* __restrict__ Wq, const float* __restrict__ Wk,
                 const float* __restrict__ Wv, const float* __restrict__ Wo,
                 const float* __restrict__ W1, const float* __restrict__ W2,
                 bf16* __restrict__ Xb, bf16* __restrict__ QKVT,
                 bf16* __restrict__ W1T, bf16* __restrict__ W2T)
{
  const int z = blockIdx.z;
  const int t = threadIdx.x;
  if (z == 12) {
    const size_t base = ((size_t)(blockIdx.y * 32 + blockIdx.x)) * 4096;
#pragma unroll
    for (int j = 0; j < 4; ++j) {
      const size_t i = base + j * 1024 + t * 4;
      f32x4 v = *(const f32x4*)(x + i);
      bf16x4 o;
#pragma unroll
      for (int k = 0; k < 4; ++k) o[k] = (bf16)v[k];
      *(bf16x4*)(Xb + i) = o;
    }
    return;
  }
  const float* ps; bf16* pd; int sld, dld;
  if (z < 4) {
    ps = (z == 0) ? Wq : (z == 1) ? Wk : (z == 2) ? Wv : Wo;
    pd = QKVT + (size_t)z * HDIM * HDIM; sld = 1024; dld = 1024;
  } else if (z < 8) {
    const int c = z - 4;
    ps = W1 + c * 1024; sld = 4096;
    pd = W1T + (size_t)c * 1024 * 1024; dld = 1024;
  } else {
    const int c = z - 8;
    ps = W2 + (size_t)c * 1024 * 1024; sld = 1024;
    pd = W2T + c * 1024; dld = 4096;
  }
  __shared__ float tile[32][33];
  const int tx = t & 31, ty = t >> 5;
  const int c0 = blockIdx.x * 32, r0 = blockIdx.y * 32;
#pragma unroll
  for (int i = 0; i < 32; i += 8)
    tile[ty + i][tx] = ps[(size_t)(r0 + ty + i) * sld + c0 + tx];
  __syncthreads();
#pragma unroll
  for (int i = 0; i < 32; i += 8)
    pd[(size_t)(c0 + ty + i) * dld + r0 + tx] = (bf16)tile[tx][ty + i];
}

// ---------------------------------------------------------------- GEMM  C = A @ Bt^T (+ bias)
// Operand-swapped MFMA: lane holds 4 consecutive output columns -> vector stores.
// EPI: 1 = f32 partial, 2 = bias+gelu->bf16, 3 = QKV fused epilogue (V -> Vt[d][s])
template<int EPI>
__global__ __launch_bounds__(256)
void gemm_bt(const bf16* __restrict__ A, const bf16* __restrict__ Bt,
             const float* __restrict__ b0, const float* __restrict__ b1p,
             const float* __restrict__ b2p, void* __restrict__ Cout,
             int M, int N, int ldk, int kchunk)
{
  __shared__ __align__(16) bf16 As[128 * 64];
  __shared__ __align__(16) bf16 Bs[128 * 64];
  const int t = threadIdx.x;
  const int wave = t >> 6, lane = t & 63;
  const int lm = lane & 15, qd = lane >> 4;
  const int wm = (wave >> 1) * 64, wn = (wave & 1) * 64;
  const int bm = blockIdx.y * 128, bn = blockIdx.x * 128;
  const int kbeg = blockIdx.z * kchunk;

  f32x4 acc[4][4] = {};
  const int srow = t >> 3;
  const int schk = t & 7;

  for (int k0 = kbeg; k0 < kbeg + kchunk; k0 += 64) {
#pragma unroll
    for (int r = 0; r < 4; ++r) {
      const int row = r * 32 + srow;
      const int chunk = schk ^ (row & 7);
      async_load16(A + (size_t)(bm + row) * ldk + (k0 + chunk * 8),
                   (bf16*)((char*)As + r * 4096 + t * 16));
    }
#pragma unroll
    for (int r = 0; r < 4; ++r) {
      const int row = r * 32 + srow;
      const int chunk = schk ^ (row & 7);
      async_load16(Bt + (size_t)(bn + row) * ldk + (k0 + chunk * 8),
                   (bf16*)((char*)Bs + r * 4096 + t * 16));
    }
    __syncthreads();
#pragma unroll
    for (int ks = 0; ks < 2; ++ks) {
      bf16x8 av[4], bv[4];
#pragma unroll
      for (int mt = 0; mt < 4; ++mt) {
        const int row = wm + mt * 16 + lm;
        const int chunk = (ks * 4 + qd) ^ (row & 7);
        av[mt] = *(const bf16x8*)(As + row * 64 + chunk * 8);
      }
#pragma unroll
      for (int nt = 0; nt < 4; ++nt) {
        const int row = wn + nt * 16 + lm;
        const int chunk = (ks * 4 + qd) ^ (row & 7);
        bv[nt] = *(const bf16x8*)(Bs + row * 64 + chunk * 8);
      }
#pragma unroll
      for (int mt = 0; mt < 4; ++mt)
#pragma unroll
        for (int nt = 0; nt < 4; ++nt)
          acc[mt][nt] = __builtin_amdgcn_mfma_f32_16x16x32_bf16(bv[nt], av[mt], acc[mt][nt], 0, 0, 0);
    }
    __syncthreads();
  }

#pragma unroll
  for (int nt = 0; nt < 4; ++nt) {
    const int n0 = bn + wn + nt * 16 + qd * 4;
    f32x4 bsv = {0.f, 0.f, 0.f, 0.f};
    if (EPI == 2) bsv = *(const f32x4*)(b0 + n0);
    if (EPI == 3) {
      const int sect = n0 >> 10, c = n0 & 1023;
      const float* bp = (sect == 0) ? b0 : (sect == 1) ? b1p : b2p;
      bsv = *(const f32x4*)(bp + c);
    }
#pragma unroll
    for (int mt = 0; mt < 4; ++mt) {
      const int m = bm + wm + mt * 16 + lm;
      f32x4 v;
#pragma unroll
      for (int r = 0; r < 4; ++r) v[r] = acc[mt][nt][r] + bsv[r];
      if (EPI == 1) {
        *(f32x4*)((float*)Cout + (size_t)blockIdx.z * M * N + (size_t)m * N + n0) = v;
      } else if (EPI == 2) {
        bf16x4 o;
#pragma unroll
        for (int r = 0; r < 4; ++r) {
          const float z = v[r] * 0.70710678118f;
          const float az = fabsf(z);
          const float tt = __builtin_amdgcn_rcpf(fmaf(az, 0.3275911f, 1.0f));
          const float poly = tt * fmaf(tt, fmaf(tt, fmaf(tt, fmaf(tt, 1.061405429f,
                             -1.453152027f), 1.421413741f), -0.284496736f), 0.254829592f);
          const float e = __builtin_amdgcn_exp2f(az * az * -1.4426950408889634f);
          float erfv = 1.0f - poly * e;
          erfv = (z < 0.f) ? -erfv : erfv;
          o[r] = (bf16)(0.5f * v[r] * (1.0f + erfv));
        }
        *(bf16x4*)((bf16*)Cout + (size_t)m * N + n0) = o;
      } else {
        bf16* base = (bf16*)Cout;
        const int sect = n0 >> 10, c = n0 & 1023;
        if (sect < 2) {
          bf16x4 o;
#pragma unroll
          for (int r = 0; r < 4; ++r) o[r] = (bf16)v[r];
          *(bf16x4*)(base + (size_t)sect * M_TOK * HDIM + (size_t)m * HDIM + c) = o;
        } else {
          const int hh = c >> 6, dd = c & 63;
          const int bb = m >> 11, ss = m & 2047;
#pragma unroll
          for (int r = 0; r < 4; ++r)
            base[(size_t)2 * M_TOK * HDIM +
                 (size_t)((bb * NHEAD + hh) * HD + dd + r) * SEQ + ss] = (bf16)v[r];
        }
      }
    }
  }
}

// ---------------------------------------------------------------- flash attention v5
// R7 structure (LDS-staged K/V shared by 4 waves, register-P via 16x16x16)
// + 32 q per wave: kf/vf fragments amortized over 2 q-tiles.
// grid (SEQ/128, 32 bh, NSPLIT), 256 thr.
__global__ __launch_bounds__(256)
void attn_kernel(const bf16* __restrict__ Q, const bf16* __restrict__ Kg,
                 const bf16* __restrict__ Vt, const int* __restrict__ mask,
                 float* __restrict__ Po, float* __restrict__ Lp)
{
  __shared__ __align__(16) bf16 Ks[64 * 64];   // [key][d], chunk-swizzled
  __shared__ __align__(16) bf16 Vs[64 * 64];   // [d][key], chunk-swizzled
  __shared__ float madd[64];

  const int t = threadIdx.x;
  const int wave = t >> 6, lane = t & 63;
  const int lm = lane & 15, qd = lane >> 4;
  const int bh = blockIdx.y;
  const int b = bh >> 4, h = bh & 15;
  const int q0 = blockIdx.x * 128 + wave * 32;
  const int split = blockIdx.z;
  const int kv_beg = split * (SEQ / NSPLIT);

  bf16x8 qf[2][2];
#pragma unroll
  for (int qt = 0; qt < 2; ++qt)
#pragma unroll
    for (int ks = 0; ks < 2; ++ks)
      qf[qt][ks] = *(const bf16x8*)(Q + (size_t)(b * SEQ + q0 + qt * 16 + lm) * HDIM +
                                    h * HD + ks * 32 + qd * 8);

  float l_lane[2] = {0.f, 0.f};
  f32x4 oacc[2][4] = {};   // [qt][nt2] O^T: d = nt2*16+qd*4+r, q = lm

  const int srow = t >> 3, schk = t & 7;
  const float C = 0.1803368801f;  // log2(e)/8

  for (int kv0 = kv_beg; kv0 < kv_beg + SEQ / NSPLIT; kv0 += 64) {
#pragma unroll
    for (int r = 0; r < 2; ++r) {
      const int row = r * 32 + srow;
      const int g = schk ^ (row & 7);
      async_load16(Kg + (size_t)(b * SEQ + kv0 + row) * HDIM + h * HD + g * 8,
                   (bf16*)((char*)Ks + r * 4096 + t * 16));
      async_load16(Vt + (size_t)(bh * HD + row) * SEQ + kv0 + g * 8,
                   (bf16*)((char*)Vs + r * 4096 + t * 16));
    }
    if (t < 64) madd[t] = (mask[b * SEQ + kv0 + t] == 1) ? 0.f : -1.0e30f;
    __syncthreads();

    // K fragments once, shared by both q-tiles
    bf16x8 kf[2][4];
#pragma unroll
    for (int ks = 0; ks < 2; ++ks)
#pragma unroll
      for (int nt = 0; nt < 4; ++nt) {
        const int row = nt * 16 + lm;
        const int c = (ks * 4 + qd) ^ (row & 7);
        kf[ks][nt] = *(const bf16x8*)(Ks + row * 64 + c * 8);
      }

    bf16x4 pf[2][4];
#pragma unroll
    for (int qt = 0; qt < 2; ++qt) {
      f32x4 sacc[4] = {};
#pragma unroll
      for (int ks = 0; ks < 2; ++ks)
#pragma unroll
        for (int nt = 0; nt < 4; ++nt)
          sacc[nt] = __builtin_amdgcn_mfma_f32_16x16x32_bf16(kf[ks][nt], qf[qt][ks], sacc[nt], 0, 0, 0);
#pragma unroll
      for (int nt = 0; nt < 4; ++nt) {
        f32x4 ma = *(const f32x4*)(madd + nt * 16 + qd * 4);
#pragma unroll
        for (int r = 0; r < 4; ++r) {
          const float pv = __builtin_amdgcn_exp2f(fmaf(sacc[nt][r], C, ma[r]));
          l_lane[qt] += pv;
          pf[qt][nt][r] = (bf16)pv;
        }
      }
    }

    // O^T += V^T @ P^T; vf fragment loaded once per (nt2,nt), used by both q-tiles
#pragma unroll
    for (int nt2 = 0; nt2 < 4; ++nt2) {
      const int row = nt2 * 16 + lm;
#pragma unroll
      for (int nt = 0; nt < 4; ++nt) {
        bf16x4 vf = *(const bf16x4*)(Vs + row * 64 +
                     (((nt * 2 + (qd >> 1)) ^ (row & 7)) * 8) + (qd & 1) * 4);
        oacc[0][nt2] = mfma16_bf16(vf, pf[0][nt], oacc[0][nt2]);
        oacc[1][nt2] = mfma16_bf16(vf, pf[1][nt], oacc[1][nt2]);
      }
    }
    __syncthreads();
  }

  float* po = Po + (size_t)(split * 32 + bh) * 64 * SEQ;
#pragma unroll
  for (int qt = 0; qt < 2; ++qt) {
    float l = l_lane[qt];
    l += __shfl_xor(l, 16, 64);
    l += __shfl_xor(l, 32, 64);
#pragma unroll
    for (int nt2 = 0; nt2 < 4; ++nt2)
#pragma unroll
      for (int r = 0; r < 4; ++r)
        po[(size_t)(nt2 * 16 + qd * 4 + r) * SEQ + q0 + qt * 16 + lm] = oacc[qt][nt2][r];
    if (qd == 0)
      Lp[(size_t)(split * 32 + bh) * SEQ + q0 + qt * 16 + lm] = l;
  }
}

// ---------------------------------------------------------------- attn merge: O=(O0+O1)/(l0+l1)
__global__ __launch_bounds__(256)
void attn_merge(const float* __restrict__ Po, const float* __restrict__ Lp,
                bf16* __restrict__ Aout)
{
  const int t = threadIdx.x;
  const int bh = blockIdx.y;
  const int b = bh >> 4, h = bh & 15;
  const int s0 = blockIdx.x * 64;
  const int tok = t >> 2;
  const int dc = (t & 3) * 16;

  const float l = Lp[(size_t)bh * SEQ + s0 + tok] +
                  Lp[(size_t)(32 + bh) * SEQ + s0 + tok];
  const float inv = 1.0f / l;

  const float* p0 = Po + ((size_t)bh * 64) * SEQ + s0 + tok;
  const float* p1 = Po + ((size_t)(32 + bh) * 64) * SEQ + s0 + tok;
  bf16x8 o0, o1;
#pragma unroll
  for (int j = 0; j < 8; ++j)
    o0[j] = (bf16)((p0[(size_t)(dc + j) * SEQ] + p1[(size_t)(dc + j) * SEQ]) * inv);
#pragma unroll
  for (int j = 8; j < 16; ++j)
    o1[j - 8] = (bf16)((p0[(size_t)(dc + j) * SEQ] + p1[(size_t)(dc + j) * SEQ]) * inv);

  bf16* dst = Aout + (size_t)(b * SEQ + s0 + tok) * HDIM + h * HD + dc;
  *(bf16x8*)dst = o0;
  *(bf16x8*)(dst + 8) = o1;
}

// ------------------------------------------- layernorm over H=1024, summing NP partials + bias
template<int NP, int OUT_BF16>
__global__ __launch_bounds__(256)
void ln_sum(const float* __restrict__ p, const float* __restrict__ bias,
            const float* __restrict__ gamma, const float* __restrict__ beta,
            void* __restrict__ out)
{
  const int row = blockIdx.x;
  const int t = threadIdx.x;
  f32x4 v = *(const f32x4*)(p + (size_t)row * HDIM + t * 4);
#pragma unroll
  for (int np = 1; np < NP; ++np) {
    f32x4 u = *(const f32x4*)(p + np * PSTRIDE + (size_t)row * HDIM + t * 4);
#pragma unroll
    for (int j = 0; j < 4; ++j) v[j] += u[j];
  }
  f32x4 bv0 = *(const f32x4*)(bias + t * 4);
#pragma unroll
  for (int j = 0; j < 4; ++j) v[j] += bv0[j];

  float s = v[0] + v[1] + v[2] + v[3];
  float s2 = v[0] * v[0] + v[1] * v[1] + v[2] * v[2] + v[3] * v[3];
#pragma unroll
  for (int d = 1; d < 64; d <<= 1) { s += __shfl_xor(s, d, 64); s2 += __shfl_xor(s2, d, 64); }
  __shared__ float ss[4], ss2[4];
  const int wave = t >> 6, lane = t & 63;
  if (lane == 0) { ss[wave] = s; ss2[wave] = s2; }
  __syncthreads();
  s = ss[0] + ss[1] + ss[2] + ss[3];
  s2 = ss2[0] + ss2[1] + ss2[2] + ss2[3];
  const float mean = s * (1.0f / HDIM);
  const float var = s2 * (1.0f / HDIM) - mean * mean;
  const float rstd = rsqrtf(var + 1e-12f);
  f32x4 gv = *(const f32x4*)(gamma + t * 4);
  f32x4 bv = *(const f32x4*)(beta + t * 4);
  f32x4 y;
#pragma unroll
  for (int j = 0; j < 4; ++j) y[j] = gv[j] * (v[j] - mean) * rstd + bv[j];
  if (OUT_BF16) {
    bf16x4 o;
#pragma unroll
    for (int j = 0; j < 4; ++j) o[j] = (bf16)y[j];
    *(bf16x4*)((bf16*)out + (size_t)row * HDIM + t * 4) = o;
  } else {
    *(f32x4*)((float*)out + (size_t)row * HDIM + t * 4) = y;
  }
}

// ---------------------------------------------------------------- launch
extern "C" void kernel_launch(void* const* d_in, const int* in_sizes, int n_in,
                              void* d_out, int out_size, void* d_ws, size_t ws_size,
                              hipStream_t stream)
{
  const float* x    = (const float*)d_in[0];
  const int*   am   = (const int*)d_in[1];
  const float* Wq   = (const float*)d_in[2];
  const float* bq   = (const float*)d_in[3];
  const float* Wk   = (const float*)d_in[4];
  const float* bk   = (const float*)d_in[5];
  const float* Wv   = (const float*)d_in[6];
  const float* bv   = (const float*)d_in[7];
  const float* Wo   = (const float*)d_in[8];
  const float* bo   = (const float*)d_in[9];
  const float* ln1g = (const float*)d_in[10];
  const float* ln1b = (const float*)d_in[11];
  const float* W1   = (const float*)d_in[12];
  const float* b1   = (const float*)d_in[13];
  const float* W2   = (const float*)d_in[14];
  const float* b2   = (const float*)d_in[15];
  const float* ln2g = (const float*)d_in[16];
  const float* ln2b = (const float*)d_in[17];

  char* ws = (char*)d_ws;
  const size_t MB = 1ull << 20;
  bf16*  W1T  = (bf16*)(ws + 0 * MB);    // 8 MiB
  bf16*  W2T  = (bf16*)(ws + 8 * MB);    // 8 MiB
  bf16*  Xb   = (bf16*)(ws + 16 * MB);   // 8 MiB (dead after QKV)
  bf16*  QKVT = (bf16*)(ws + 24 * MB);   // 8 MiB (WoT = last quarter)
  bf16*  WoT  = QKVT + (size_t)3 * HDIM * HDIM;
  bf16*  Qb   = (bf16*)(ws + 33 * MB);   // Q(33-41), K(41-49), Vt(49-57)
  bf16*  Kb   = (bf16*)(ws + 41 * MB);
  bf16*  Vtb  = (bf16*)(ws + 49 * MB);
  float* Po   = (float*)(ws + 57 * MB);  // 32 MiB attn O^T partials (57-89)
  float* Lp   = (float*)(ws + 89 * MB);  // 0.5 MiB l partials
  bf16*  Ab   = (bf16*)(ws + 16 * MB);   // merge out, reuse Xb
  float* Pw   = (float*)(ws + 33 * MB);  // Wo partials 33-65
  bf16*  L1   = (bf16*)(ws + 65 * MB);   // 8 MiB
  bf16*  F1   = (bf16*)(ws + 16 * MB);   // 32 MiB (16-48)
  float* Pf   = (float*)(ws + 48 * MB);  // FFN2 partials

  prep_kernel<<<dim3(32, 32, 13), 256, 0, stream>>>(x, Wq, Wk, Wv, Wo, W1, W2,
                                                    Xb, QKVT, W1T, W2T);

  gemm_bt<3><<<dim3(3072 / 128, M_TOK / 128, 1), 256, 0, stream>>>(
      Xb, QKVT, bq, bk, bv, Qb, M_TOK, 3072, HDIM, HDIM);

  attn_kernel<<<dim3(SEQ / 128, BATCH * NHEAD, NSPLIT), 256, 0, stream>>>(
      Qb, Kb, Vtb, am, Po, Lp);
  attn_merge<<<dim3(SEQ / 64, BATCH * NHEAD), 256, 0, stream>>>(Po, Lp, Ab);

  gemm_bt<1><<<dim3(HDIM / 128, M_TOK / 128, 2), 256, 0, stream>>>(
      Ab, WoT, nullptr, nullptr, nullptr, Pw, M_TOK, HDIM, HDIM, 512);
  ln_sum<2, 1><<<M_TOK, 256, 0, stream>>>(Pw, bo, ln1g, ln1b, L1);

  gemm_bt<2><<<dim3(FFDIM / 128, M_TOK / 128, 1), 256, 0, stream>>>(
      L1, W1T, b1, nullptr, nullptr, F1, M_TOK, FFDIM, HDIM, HDIM);

  if (ws_size >= 113 * MB) {
    gemm_bt<1><<<dim3(HDIM / 128, M_TOK / 128, 4), 256, 0, stream>>>(
        F1, W2T, nullptr, nullptr, nullptr, Pf, M_TOK, HDIM, FFDIM, 1024);
    ln_sum<4, 0><<<M_TOK, 256, 0, stream>>>(Pf, b2, ln2g, ln2b, (float*)d_out);
  } else {
    gemm_bt<1><<<dim3(HDIM / 128, M_TOK / 128, 2), 256, 0, stream>>>(
        F1, W2T, nullptr, nullptr, nullptr, Pf, M_TOK, HDIM, FFDIM, 2048);
    ln_sum<2, 0><<<M_TOK, 256, 0, stream>>>(Pf, b2, ln2g, ln2b, (float*)d_out);
  }
}

// Round 10
// 375.274 us; speedup vs baseline: 1.1177x; 1.0136x over previous
//
#include <hip/hip_runtime.h>
#include <hip/hip_bf16.h>
#include <math.h>

typedef __bf16 bf16;
typedef __attribute__((ext_vector_type(8))) __bf16 bf16x8;
typedef __attribute__((ext_vector_type(4))) __bf16 bf16x4;
typedef __attribute__((ext_vector_type(4))) float f32x4;
typedef __attribute__((ext_vector_type(4))) short short4v;

#define HDIM 1024
#define NHEAD 16
#define HD 64
#define FFDIM 4096
#define BATCH 2
#define SEQ 2048
#define M_TOK 4096  // BATCH*SEQ
#define NSPLIT 4
#define PSTRIDE ((size_t)M_TOK * HDIM)  // elements between split-K partials

static __device__ __forceinline__ void async_load16(const bf16* g, bf16* l) {
  __builtin_amdgcn_global_load_lds(
      (const __attribute__((address_space(1))) void*)g,
      (__attribute__((address_space(3))) void*)l, 16, 0, 0);
}

// 16x16x16 bf16 MFMA wrapper. Host pass has no amdgcn builtins -> gate on
// __HIP_DEVICE_COMPILE__ (R5 lesson).
static __device__ __forceinline__ f32x4 mfma16_bf16(bf16x4 a, bf16x4 b, f32x4 c) {
#if defined(__HIP_DEVICE_COMPILE__)
#if __has_builtin(__builtin_amdgcn_mfma_f32_16x16x16bf16_1k)
  return __builtin_amdgcn_mfma_f32_16x16x16bf16_1k(
      __builtin_bit_cast(short4v, a), __builtin_bit_cast(short4v, b), c, 0, 0, 0);
#else
  return __builtin_amdgcn_mfma_f32_16x16x16_bf16(a, b, c, 0, 0, 0);
#endif
#else
  return c;  // host pass: never executed
#endif
}

// ---------------------------------------------------------------- prep: all transposes + x cast
__global__ __launch_bounds__(256)
void prep_kernel(const float* __restrict__ x,
                 const float* __restrict__ Wq, const float* __restrict__ Wk,
                 const float* __restrict__ Wv, const float* __restrict__ Wo,
                 const float* __restrict__ W1, const float* __restrict__ W2,
                 bf16* __restrict__ Xb, bf16* __restrict__ QKVT,
                 bf16* __restrict__ W1T, bf16* __restrict__ W2T)
{
  const int z = blockIdx.z;
  const int t = threadIdx.x;
  if (z == 12) {
    const size_t base = ((size_t)(blockIdx.y * 32 + blockIdx.x)) * 4096;
#pragma unroll
    for (int j = 0; j < 4; ++j) {
      const size_t i = base + j * 1024 + t * 4;
      f32x4 v = *(const f32x4*)(x + i);
      bf16x4 o;
#pragma unroll
      for (int k = 0; k < 4; ++k) o[k] = (bf16)v[k];
      *(bf16x4*)(Xb + i) = o;
    }
    return;
  }
  const float* ps; bf16* pd; int sld, dld;
  if (z < 4) {
    ps = (z == 0) ? Wq : (z == 1) ? Wk : (z == 2) ? Wv : Wo;
    pd = QKVT + (size_t)z * HDIM * HDIM; sld = 1024; dld = 1024;
  } else if (z < 8) {
    const int c = z - 4;
    ps = W1 + c * 1024; sld = 4096;
    pd = W1T + (size_t)c * 1024 * 1024; dld = 1024;
  } else {
    const int c = z - 8;
    ps = W2 + (size_t)c * 1024 * 1024; sld = 1024;
    pd = W2T + c * 1024; dld = 4096;
  }
  __shared__ float tile[32][33];
  const int tx = t & 31, ty = t >> 5;
  const int c0 = blockIdx.x * 32, r0 = blockIdx.y * 32;
#pragma unroll
  for (int i = 0; i < 32; i += 8)
    tile[ty + i][tx] = ps[(size_t)(r0 + ty + i) * sld + c0 + tx];
  __syncthreads();
#pragma unroll
  for (int i = 0; i < 32; i += 8)
    pd[(size_t)(c0 + ty + i) * dld + r0 + tx] = (bf16)tile[tx][ty + i];
}

// ---------------------------------------------------------------- GEMM  C = A @ Bt^T (+ bias)
// Operand-swapped MFMA: lane holds 4 consecutive output columns -> vector stores.
// EPI: 1 = bf16 partial (no bias, out + z*M*N), 2 = bias+gelu->bf16,
//      3 = QKV fused epilogue (V -> Vt[d][s])
template<int EPI>
__global__ __launch_bounds__(256)
void gemm_bt(const bf16* __restrict__ A, const bf16* __restrict__ Bt,
             const float* __restrict__ b0, const float* __restrict__ b1p,
             const float* __restrict__ b2p, void* __restrict__ Cout,
             int M, int N, int ldk, int kchunk)
{
  __shared__ __align__(16) bf16 As[128 * 64];
  __shared__ __align__(16) bf16 Bs[128 * 64];
  const int t = threadIdx.x;
  const int wave = t >> 6, lane = t & 63;
  const int lm = lane & 15, qd = lane >> 4;
  const int wm = (wave >> 1) * 64, wn = (wave & 1) * 64;
  const int bm = blockIdx.y * 128, bn = blockIdx.x * 128;
  const int kbeg = blockIdx.z * kchunk;

  f32x4 acc[4][4] = {};
  const int srow = t >> 3;
  const int schk = t & 7;

  for (int k0 = kbeg; k0 < kbeg + kchunk; k0 += 64) {
#pragma unroll
    for (int r = 0; r < 4; ++r) {
      const int row = r * 32 + srow;
      const int chunk = schk ^ (row & 7);
      async_load16(A + (size_t)(bm + row) * ldk + (k0 + chunk * 8),
                   (bf16*)((char*)As + r * 4096 + t * 16));
    }
#pragma unroll
    for (int r = 0; r < 4; ++r) {
      const int row = r * 32 + srow;
      const int chunk = schk ^ (row & 7);
      async_load16(Bt + (size_t)(bn + row) * ldk + (k0 + chunk * 8),
                   (bf16*)((char*)Bs + r * 4096 + t * 16));
    }
    __syncthreads();
#pragma unroll
    for (int ks = 0; ks < 2; ++ks) {
      bf16x8 av[4], bv[4];
#pragma unroll
      for (int mt = 0; mt < 4; ++mt) {
        const int row = wm + mt * 16 + lm;
        const int chunk = (ks * 4 + qd) ^ (row & 7);
        av[mt] = *(const bf16x8*)(As + row * 64 + chunk * 8);
      }
#pragma unroll
      for (int nt = 0; nt < 4; ++nt) {
        const int row = wn + nt * 16 + lm;
        const int chunk = (ks * 4 + qd) ^ (row & 7);
        bv[nt] = *(const bf16x8*)(Bs + row * 64 + chunk * 8);
      }
#pragma unroll
      for (int mt = 0; mt < 4; ++mt)
#pragma unroll
        for (int nt = 0; nt < 4; ++nt)
          acc[mt][nt] = __builtin_amdgcn_mfma_f32_16x16x32_bf16(bv[nt], av[mt], acc[mt][nt], 0, 0, 0);
    }
    __syncthreads();
  }

#pragma unroll
  for (int nt = 0; nt < 4; ++nt) {
    const int n0 = bn + wn + nt * 16 + qd * 4;
    f32x4 bsv = {0.f, 0.f, 0.f, 0.f};
    if (EPI == 2) bsv = *(const f32x4*)(b0 + n0);
    if (EPI == 3) {
      const int sect = n0 >> 10, c = n0 & 1023;
      const float* bp = (sect == 0) ? b0 : (sect == 1) ? b1p : b2p;
      bsv = *(const f32x4*)(bp + c);
    }
#pragma unroll
    for (int mt = 0; mt < 4; ++mt) {
      const int m = bm + wm + mt * 16 + lm;
      f32x4 v;
#pragma unroll
      for (int r = 0; r < 4; ++r) v[r] = acc[mt][nt][r] + bsv[r];
      if (EPI == 1) {
        bf16x4 o;
#pragma unroll
        for (int r = 0; r < 4; ++r) o[r] = (bf16)v[r];
        *(bf16x4*)((bf16*)Cout + (size_t)blockIdx.z * M * N + (size_t)m * N + n0) = o;
      } else if (EPI == 2) {
        bf16x4 o;
#pragma unroll
        for (int r = 0; r < 4; ++r) {
          const float z = v[r] * 0.70710678118f;
          const float az = fabsf(z);
          const float tt = __builtin_amdgcn_rcpf(fmaf(az, 0.3275911f, 1.0f));
          const float poly = tt * fmaf(tt, fmaf(tt, fmaf(tt, fmaf(tt, 1.061405429f,
                             -1.453152027f), 1.421413741f), -0.284496736f), 0.254829592f);
          const float e = __builtin_amdgcn_exp2f(az * az * -1.4426950408889634f);
          float erfv = 1.0f - poly * e;
          erfv = (z < 0.f) ? -erfv : erfv;
          o[r] = (bf16)(0.5f * v[r] * (1.0f + erfv));
        }
        *(bf16x4*)((bf16*)Cout + (size_t)m * N + n0) = o;
      } else {
        bf16* base = (bf16*)Cout;
        const int sect = n0 >> 10, c = n0 & 1023;
        if (sect < 2) {
          bf16x4 o;
#pragma unroll
          for (int r = 0; r < 4; ++r) o[r] = (bf16)v[r];
          *(bf16x4*)(base + (size_t)sect * M_TOK * HDIM + (size_t)m * HDIM + c) = o;
        } else {
          const int hh = c >> 6, dd = c & 63;
          const int bb = m >> 11, ss = m & 2047;
#pragma unroll
          for (int r = 0; r < 4; ++r)
            base[(size_t)2 * M_TOK * HDIM +
                 (size_t)((bb * NHEAD + hh) * HD + dd + r) * SEQ + ss] = (bf16)v[r];
        }
      }
    }
  }
}

// ---------------------------------------------------------------- flash attention v6
// R9 structure (LDS-staged K/V, register-P, 32 q/wave) + NSPLIT=4 for block
// concurrency + bf16 unnormalized O^T partials (halves Po traffic).
// grid (SEQ/128, 32 bh, NSPLIT), 256 thr.
__global__ __launch_bounds__(256)
void attn_kernel(const bf16* __restrict__ Q, const bf16* __restrict__ Kg,
                 const bf16* __restrict__ Vt, const int* __restrict__ mask,
                 bf16* __restrict__ Po, float* __restrict__ Lp)
{
  __shared__ __align__(16) bf16 Ks[64 * 64];   // [key][d], chunk-swizzled
  __shared__ __align__(16) bf16 Vs[64 * 64];   // [d][key], chunk-swizzled
  __shared__ float madd[64];

  const int t = threadIdx.x;
  const int wave = t >> 6, lane = t & 63;
  const int lm = lane & 15, qd = lane >> 4;
  const int bh = blockIdx.y;
  const int b = bh >> 4, h = bh & 15;
  const int q0 = blockIdx.x * 128 + wave * 32;
  const int split = blockIdx.z;
  const int kv_beg = split * (SEQ / NSPLIT);

  bf16x8 qf[2][2];
#pragma unroll
  for (int qt = 0; qt < 2; ++qt)
#pragma unroll
    for (int ks = 0; ks < 2; ++ks)
      qf[qt][ks] = *(const bf16x8*)(Q + (size_t)(b * SEQ + q0 + qt * 16 + lm) * HDIM +
                                    h * HD + ks * 32 + qd * 8);

  float l_lane[2] = {0.f, 0.f};
  f32x4 oacc[2][4] = {};   // [qt][nt2] O^T: d = nt2*16+qd*4+r, q = lm

  const int srow = t >> 3, schk = t & 7;
  const float C = 0.1803368801f;  // log2(e)/8

  for (int kv0 = kv_beg; kv0 < kv_beg + SEQ / NSPLIT; kv0 += 64) {
#pragma unroll
    for (int r = 0; r < 2; ++r) {
      const int row = r * 32 + srow;
      const int g = schk ^ (row & 7);
      async_load16(Kg + (size_t)(b * SEQ + kv0 + row) * HDIM + h * HD + g * 8,
                   (bf16*)((char*)Ks + r * 4096 + t * 16));
      async_load16(Vt + (size_t)(bh * HD + row) * SEQ + kv0 + g * 8,
                   (bf16*)((char*)Vs + r * 4096 + t * 16));
    }
    if (t < 64) madd[t] = (mask[b * SEQ + kv0 + t] == 1) ? 0.f : -1.0e30f;
    __syncthreads();

    bf16x8 kf[2][4];
#pragma unroll
    for (int ks = 0; ks < 2; ++ks)
#pragma unroll
      for (int nt = 0; nt < 4; ++nt) {
        const int row = nt * 16 + lm;
        const int c = (ks * 4 + qd) ^ (row & 7);
        kf[ks][nt] = *(const bf16x8*)(Ks + row * 64 + c * 8);
      }

    bf16x4 pf[2][4];
#pragma unroll
    for (int qt = 0; qt < 2; ++qt) {
      f32x4 sacc[4] = {};
#pragma unroll
      for (int ks = 0; ks < 2; ++ks)
#pragma unroll
        for (int nt = 0; nt < 4; ++nt)
          sacc[nt] = __builtin_amdgcn_mfma_f32_16x16x32_bf16(kf[ks][nt], qf[qt][ks], sacc[nt], 0, 0, 0);
#pragma unroll
      for (int nt = 0; nt < 4; ++nt) {
        f32x4 ma = *(const f32x4*)(madd + nt * 16 + qd * 4);
#pragma unroll
        for (int r = 0; r < 4; ++r) {
          const float pv = __builtin_amdgcn_exp2f(fmaf(sacc[nt][r], C, ma[r]));
          l_lane[qt] += pv;
          pf[qt][nt][r] = (bf16)pv;
        }
      }
    }

#pragma unroll
    for (int nt2 = 0; nt2 < 4; ++nt2) {
      const int row = nt2 * 16 + lm;
#pragma unroll
      for (int nt = 0; nt < 4; ++nt) {
        bf16x4 vf = *(const bf16x4*)(Vs + row * 64 +
                     (((nt * 2 + (qd >> 1)) ^ (row & 7)) * 8) + (qd & 1) * 4);
        oacc[0][nt2] = mfma16_bf16(vf, pf[0][nt], oacc[0][nt2]);
        oacc[1][nt2] = mfma16_bf16(vf, pf[1][nt], oacc[1][nt2]);
      }
    }
    __syncthreads();
  }

  bf16* po = Po + (size_t)(split * 32 + bh) * 64 * SEQ;
#pragma unroll
  for (int qt = 0; qt < 2; ++qt) {
    float l = l_lane[qt];
    l += __shfl_xor(l, 16, 64);
    l += __shfl_xor(l, 32, 64);
#pragma unroll
    for (int nt2 = 0; nt2 < 4; ++nt2)
#pragma unroll
      for (int r = 0; r < 4; ++r)
        po[(size_t)(nt2 * 16 + qd * 4 + r) * SEQ + q0 + qt * 16 + lm] =
            (bf16)oacc[qt][nt2][r];
    if (qd == 0)
      Lp[(size_t)(split * 32 + bh) * SEQ + q0 + qt * 16 + lm] = l;
  }
}

// ---------------------------------------------------------------- attn merge: O = (sum Po_s)/(sum l_s)
__global__ __launch_bounds__(256)
void attn_merge(const bf16* __restrict__ Po, const float* __restrict__ Lp,
                bf16* __restrict__ Aout)
{
  const int t = threadIdx.x;
  const int bh = blockIdx.y;
  const int b = bh >> 4, h = bh & 15;
  const int s0 = blockIdx.x * 64;
  const int tok = t >> 2;
  const int dc = (t & 3) * 16;

  float l = 0.f;
#pragma unroll
  for (int s = 0; s < NSPLIT; ++s)
    l += Lp[(size_t)(s * 32 + bh) * SEQ + s0 + tok];
  const float inv = 1.0f / l;

  const bf16* ps[NSPLIT];
#pragma unroll
  for (int s = 0; s < NSPLIT; ++s)
    ps[s] = Po + (size_t)(s * 32 + bh) * 64 * SEQ + s0 + tok;

  bf16x8 o0, o1;
#pragma unroll
  for (int j = 0; j < 16; ++j) {
    float acc = 0.f;
#pragma unroll
    for (int s = 0; s < NSPLIT; ++s)
      acc += (float)ps[s][(size_t)(dc + j) * SEQ];
    const bf16 ov = (bf16)(acc * inv);
    if (j < 8) o0[j] = ov; else o1[j - 8] = ov;
  }

  bf16* dst = Aout + (size_t)(b * SEQ + s0 + tok) * HDIM + h * HD + dc;
  *(bf16x8*)dst = o0;
  *(bf16x8*)(dst + 8) = o1;
}

// ------------------------------- layernorm over H=1024, summing NP bf16 partials + bias
template<int NP, int OUT_BF16>
__global__ __launch_bounds__(256)
void ln_sum(const bf16* __restrict__ p, const float* __restrict__ bias,
            const float* __restrict__ gamma, const float* __restrict__ beta,
            void* __restrict__ out)
{
  const int row = blockIdx.x;
  const int t = threadIdx.x;
  f32x4 v = {0.f, 0.f, 0.f, 0.f};
#pragma unroll
  for (int np = 0; np < NP; ++np) {
    bf16x4 u = *(const bf16x4*)(p + np * PSTRIDE + (size_t)row * HDIM + t * 4);
#pragma unroll
    for (int j = 0; j < 4; ++j) v[j] += (float)u[j];
  }
  f32x4 bv0 = *(const f32x4*)(bias + t * 4);
#pragma unroll
  for (int j = 0; j < 4; ++j) v[j] += bv0[j];

  float s = v[0] + v[1] + v[2] + v[3];
  float s2 = v[0] * v[0] + v[1] * v[1] + v[2] * v[2] + v[3] * v[3];
#pragma unroll
  for (int d = 1; d < 64; d <<= 1) { s += __shfl_xor(s, d, 64); s2 += __shfl_xor(s2, d, 64); }
  __shared__ float ss[4], ss2[4];
  const int wave = t >> 6, lane = t & 63;
  if (lane == 0) { ss[wave] = s; ss2[wave] = s2; }
  __syncthreads();
  s = ss[0] + ss[1] + ss[2] + ss[3];
  s2 = ss2[0] + ss2[1] + ss2[2] + ss2[3];
  const float mean = s * (1.0f / HDIM);
  const float var = s2 * (1.0f / HDIM) - mean * mean;
  const float rstd = rsqrtf(var + 1e-12f);
  f32x4 gv = *(const f32x4*)(gamma + t * 4);
  f32x4 bv = *(const f32x4*)(beta + t * 4);
  f32x4 y;
#pragma unroll
  for (int j = 0; j < 4; ++j) y[j] = gv[j] * (v[j] - mean) * rstd + bv[j];
  if (OUT_BF16) {
    bf16x4 o;
#pragma unroll
    for (int j = 0; j < 4; ++j) o[j] = (bf16)y[j];
    *(bf16x4*)((bf16*)out + (size_t)row * HDIM + t * 4) = o;
  } else {
    *(f32x4*)((float*)out + (size_t)row * HDIM + t * 4) = y;
  }
}

// ---------------------------------------------------------------- launch
extern "C" void kernel_launch(void* const* d_in, const int* in_sizes, int n_in,
                              void* d_out, int out_size, void* d_ws, size_t ws_size,
                              hipStream_t stream)
{
  const float* x    = (const float*)d_in[0];
  const int*   am   = (const int*)d_in[1];
  const float* Wq   = (const float*)d_in[2];
  const float* bq   = (const float*)d_in[3];
  const float* Wk   = (const float*)d_in[4];
  const float* bk   = (const float*)d_in[5];
  const float* Wv   = (const float*)d_in[6];
  const float* bv   = (const float*)d_in[7];
  const float* Wo   = (const float*)d_in[8];
  const float* bo   = (const float*)d_in[9];
  const float* ln1g = (const float*)d_in[10];
  const float* ln1b = (const float*)d_in[11];
  const float* W1   = (const float*)d_in[12];
  const float* b1   = (const float*)d_in[13];
  const float* W2   = (const float*)d_in[14];
  const float* b2   = (const float*)d_in[15];
  const float* ln2g = (const float*)d_in[16];
  const float* ln2b = (const float*)d_in[17];

  char* ws = (char*)d_ws;
  const size_t MB = 1ull << 20;
  bf16*  W1T  = (bf16*)(ws + 0 * MB);    // 8 MiB
  bf16*  W2T  = (bf16*)(ws + 8 * MB);    // 8 MiB
  bf16*  Xb   = (bf16*)(ws + 16 * MB);   // 8 MiB (dead after QKV)
  bf16*  QKVT = (bf16*)(ws + 24 * MB);   // 8 MiB (WoT = last quarter)
  bf16*  WoT  = QKVT + (size_t)3 * HDIM * HDIM;
  bf16*  Qb   = (bf16*)(ws + 33 * MB);   // Q(33-41), K(41-49), Vt(49-57)
  bf16*  Kb   = (bf16*)(ws + 41 * MB);
  bf16*  Vtb  = (bf16*)(ws + 49 * MB);
  bf16*  Po   = (bf16*)(ws + 57 * MB);   // 32 MiB attn O^T bf16 partials (57-89)
  float* Lp   = (float*)(ws + 89 * MB);  // 1 MiB l partials (4 splits)
  bf16*  Ab   = (bf16*)(ws + 16 * MB);   // merge out, reuse Xb
  bf16*  Pw   = (bf16*)(ws + 33 * MB);   // Wo bf16 partials 33-49 (Q/K dead)
  bf16*  L1   = (bf16*)(ws + 65 * MB);   // 8 MiB
  bf16*  F1   = (bf16*)(ws + 16 * MB);   // 32 MiB (16-48)
  bf16*  Pf   = (bf16*)(ws + 48 * MB);   // FFN2 bf16 partials 48-80

  prep_kernel<<<dim3(32, 32, 13), 256, 0, stream>>>(x, Wq, Wk, Wv, Wo, W1, W2,
                                                    Xb, QKVT, W1T, W2T);

  gemm_bt<3><<<dim3(3072 / 128, M_TOK / 128, 1), 256, 0, stream>>>(
      Xb, QKVT, bq, bk, bv, Qb, M_TOK, 3072, HDIM, HDIM);

  attn_kernel<<<dim3(SEQ / 128, BATCH * NHEAD, NSPLIT), 256, 0, stream>>>(
      Qb, Kb, Vtb, am, Po, Lp);
  attn_merge<<<dim3(SEQ / 64, BATCH * NHEAD), 256, 0, stream>>>(Po, Lp, Ab);

  gemm_bt<1><<<dim3(HDIM / 128, M_TOK / 128, 2), 256, 0, stream>>>(
      Ab, WoT, nullptr, nullptr, nullptr, Pw, M_TOK, HDIM, HDIM, 512);
  ln_sum<2, 1><<<M_TOK, 256, 0, stream>>>(Pw, bo, ln1g, ln1b, L1);

  gemm_bt<2><<<dim3(FFDIM / 128, M_TOK / 128, 1), 256, 0, stream>>>(
      L1, W1T, b1, nullptr, nullptr, F1, M_TOK, FFDIM, HDIM, HDIM);

  gemm_bt<1><<<dim3(HDIM / 128, M_TOK / 128, 4), 256, 0, stream>>>(
      F1, W2T, nullptr, nullptr, nullptr, Pf, M_TOK, HDIM, FFDIM, 1024);
  ln_sum<4, 0><<<M_TOK, 256, 0, stream>>>(Pf, b2, ln2g, ln2b, (float*)d_out);
}